// Round 4
// baseline (1412.371 us; speedup 1.0000x reference)
//
#include <hip/hip_runtime.h>
#include <math.h>

#define N_NODES 200000
#define T_TREES 2000
#define S_NODES 100
#define F_DIM 256
#define H_DIM 256
#define G_DIM 768   // 3*H
#define D_MAX 32    // upper bound on number of depth layers (actual ~17)

typedef __attribute__((ext_vector_type(8))) short short8b;   // 8 bf16 = 4 VGPR
typedef __attribute__((ext_vector_type(4))) float f32x4;

static __device__ __forceinline__ unsigned short f2bf(float x) {
    unsigned u = __float_as_uint(x);
    u += 0x7FFFu + ((u >> 16) & 1u);   // round-to-nearest-even
    return (unsigned short)(u >> 16);
}
static __device__ __forceinline__ float bf2f(unsigned short u) {
    return __uint_as_float(((unsigned)u) << 16);
}

// ---------------------------------------------------------------------------
__global__ void k_zero(float4* __restrict__ p, int n4) {
    float4 z = make_float4(0.f, 0.f, 0.f, 0.f);
    for (int i = blockIdx.x * blockDim.x + threadIdx.x; i < n4;
         i += gridDim.x * blockDim.x)
        p[i] = z;
}

// M = min{ p >= T : layer_nodes[p] < N } ; layer 0 is exactly the T roots,
// so the first valid position past them is the start of layer 1 = row width M.
__global__ void k_findM(const int* __restrict__ ln, int LM, int* __restrict__ Mdev) {
    int local = 0x7F7F7F7F;
    for (int p = T_TREES + blockIdx.x * blockDim.x + threadIdx.x; p < LM;
         p += gridDim.x * blockDim.x)
        if (ln[p] < N_NODES && p < local) local = p;
#pragma unroll
    for (int off = 32; off; off >>= 1) {
        int o = __shfl_down(local, off);
        if (o < local) local = o;
    }
    __shared__ int wmin[4];
    if ((threadIdx.x & 63) == 0) wmin[threadIdx.x >> 6] = local;
    __syncthreads();
    if (threadIdx.x == 0) {
        int m = wmin[0];
        for (int i = 1; i < 4; ++i) if (wmin[i] < m) m = wmin[i];
        if (m < 0x7F7F7F7F) atomicMin(Mdev, m);
    }
}

// layer_cnt[d] = number of valid nodes in layer d (valid entries are a
// contiguous prefix of each row by construction).
__global__ void k_hist(const int* __restrict__ ln, const int* __restrict__ Mdev,
                       int* __restrict__ layer_cnt, int LM) {
    __shared__ int h[D_MAX];
    if (threadIdx.x < D_MAX) h[threadIdx.x] = 0;
    __syncthreads();
    const int M = Mdev[0];
    for (int p = blockIdx.x * blockDim.x + threadIdx.x; p < LM;
         p += gridDim.x * blockDim.x)
        if (ln[p] < N_NODES) {
            int d = p / M;
            if (d < D_MAX) atomicAdd(&h[d], 1);
        }
    __syncthreads();
    if (threadIdx.x < D_MAX && h[threadIdx.x])
        atomicAdd(&layer_cnt[threadIdx.x], h[threadIdx.x]);
}

// Convert both weight matrices to bf16 (row-major [g][k]).
__global__ void k_convw(const float* __restrict__ wi, const float* __restrict__ wh,
                        unsigned short* __restrict__ wib, unsigned short* __restrict__ whb) {
    int i = blockIdx.x * blockDim.x + threadIdx.x;
    if (i < G_DIM * F_DIM) {
        wib[i] = f2bf(wi[i]);
        whb[i] = f2bf(wh[i]);
    }
}

// ---------------------------------------------------------------------------
// One-shot GEMM: gi_all[m][g] = (sum_k x[m][k] * w_ih[g][k]) + b_ih[g]  (bf16)
// B tile staged in LDS (shared by all 4 waves); swapped MFMA operands so regs
// hold 4 consecutive g -> 8B packed stores.
// ---------------------------------------------------------------------------
__global__ __launch_bounds__(256) void k_gemm_x(
    const float* __restrict__ x,
    const unsigned short* __restrict__ wib,
    const float* __restrict__ b_ih,
    unsigned short* __restrict__ gi_all) {
    __shared__ unsigned short Bs[64][264];   // 64 gates x 256 k (+8 pad)

    const int tid = threadIdx.x;
    const int wv = tid >> 6, lane = tid & 63;
    const int lr = lane & 15, kg = lane >> 4;
    const long m0 = (long)blockIdx.x * 256 + wv * 64;

    short8b A[4][8];
#pragma unroll
    for (int ms = 0; ms < 4; ++ms) {
        long r = m0 + ms * 16 + lr;
        if (r > N_NODES - 1) r = N_NODES - 1;
        const float* xp = x + r * F_DIM + kg * 8;
#pragma unroll
        for (int ks = 0; ks < 8; ++ks) {
            float4 u = *(const float4*)(xp + ks * 32);
            float4 v = *(const float4*)(xp + ks * 32 + 4);
            short8b t;
            t[0] = f2bf(u.x); t[1] = f2bf(u.y); t[2] = f2bf(u.z); t[3] = f2bf(u.w);
            t[4] = f2bf(v.x); t[5] = f2bf(v.y); t[6] = f2bf(v.z); t[7] = f2bf(v.w);
            A[ms][ks] = t;
        }
    }

    const int gq = tid >> 2;          // 0..63 gate row within tile
    const int kb = (tid & 3) * 64;    // 64 ushorts per thread

    const f32x4 zf = {0.f, 0.f, 0.f, 0.f};
    for (int nt = 0; nt < 12; ++nt) {
        __syncthreads();   // previous iteration's Bs reads done
        {
            const unsigned short* src = wib + (size_t)(nt * 64 + gq) * F_DIM + kb;
#pragma unroll
            for (int i = 0; i < 8; ++i)
                *(short8b*)&Bs[gq][kb + i * 8] = *(const short8b*)(src + i * 8);
        }
        __syncthreads();

        f32x4 acc[4][4];   // [ms][ns]; regs = g-dim, lanes = m-dim (swapped)
#pragma unroll
        for (int ms = 0; ms < 4; ++ms)
#pragma unroll
            for (int ns = 0; ns < 4; ++ns) acc[ms][ns] = zf;

#pragma unroll
        for (int ks = 0; ks < 8; ++ks) {
            short8b B[4];
#pragma unroll
            for (int ns = 0; ns < 4; ++ns)
                B[ns] = *(const short8b*)&Bs[ns * 16 + lr][ks * 32 + kg * 8];
#pragma unroll
            for (int ms = 0; ms < 4; ++ms)
#pragma unroll
                for (int ns = 0; ns < 4; ++ns)
                    acc[ms][ns] = __builtin_amdgcn_mfma_f32_16x16x32_bf16(
                        B[ns], A[ms][ks], acc[ms][ns], 0, 0, 0);
        }

        float4 bi[4];
#pragma unroll
        for (int ns = 0; ns < 4; ++ns)
            bi[ns] = *(const float4*)(b_ih + nt * 64 + ns * 16 + kg * 4);

#pragma unroll
        for (int ms = 0; ms < 4; ++ms) {
            long m = m0 + ms * 16 + lr;
            if (m < N_NODES) {
#pragma unroll
                for (int ns = 0; ns < 4; ++ns) {
                    int g0 = nt * 64 + ns * 16 + kg * 4;
                    ushort4 pk;
                    pk.x = f2bf(acc[ms][ns][0] + bi[ns].x);
                    pk.y = f2bf(acc[ms][ns][1] + bi[ns].y);
                    pk.z = f2bf(acc[ms][ns][2] + bi[ns].z);
                    pk.w = f2bf(acc[ms][ns][3] + bi[ns].w);
                    *(ushort4*)(gi_all + m * G_DIM + g0) = pk;
                }
            }
        }
    }
}

// ---------------------------------------------------------------------------
// One depth layer: for each valid node in layer d, h_prev = mean(children h),
// gates_h = h_prev @ w_hh^T, GRU with precomputed gi, write h (bf16) or the
// root output (fp32, d==0). Gather-based: no atomics, no cross-block deps.
// Tile = 16 nodes; 4 waves split the 768 gate cols (64 each per gate chunk).
// ---------------------------------------------------------------------------
__global__ __launch_bounds__(256) void k_layer(
    const int* __restrict__ layer_nodes,
    const int* __restrict__ child_idx,
    const int* __restrict__ child_cnt,
    const int* __restrict__ Mdev,
    const int* __restrict__ layer_cnt,
    const unsigned short* __restrict__ whb,
    const unsigned short* __restrict__ gi_all,
    const float* __restrict__ b_hh,
    unsigned short* __restrict__ h_all,
    float* __restrict__ out,
    int d, int C) {
    __shared__ unsigned short Ab[16][264];  // h_prev bf16 (padded)
    __shared__ float Hp[16][260];           // h_prev fp32 (padded)
    __shared__ int Nd[16];

    const int cntd = layer_cnt[d];
    if (cntd == 0) return;
    const int M = Mdev[0];
    const int ntiles = (cntd + 15) >> 4;
    const long pbase0 = (long)d * M;

    const int tid = threadIdx.x;
    const int wv = tid >> 6, lane = tid & 63;
    const int lr = lane & 15, kg = lane >> 4;
    const int cb = wv * 64;

    float bh[3][4];
#pragma unroll
    for (int c = 0; c < 3; ++c)
#pragma unroll
        for (int ns = 0; ns < 4; ++ns)
            bh[c][ns] = b_hh[c * 256 + cb + ns * 16 + lr];

    const int srow = tid >> 4;
    const int scol = (tid & 15) * 16;

    for (int tile = blockIdx.x; tile < ntiles; tile += gridDim.x) {
        __syncthreads();   // previous tile's LDS reads done
        // ---- gather staging: h_prev = mean(children h) ----
        {
            int idx = tile * 16 + srow;
            int node = (idx < cntd) ? layer_nodes[pbase0 + idx] : N_NODES;
            if ((tid & 15) == 0) Nd[srow] = node;
            float sum[16];
#pragma unroll
            for (int i = 0; i < 16; ++i) sum[i] = 0.f;
            if (node < N_NODES) {
                int cc = child_cnt[pbase0 + idx];
                const int* ch = child_idx + (size_t)(pbase0 + idx) * C;
                for (int c = 0; c < cc; ++c) {
                    int kid = ch[c];
                    const unsigned short* hr = h_all + (size_t)kid * H_DIM + scol;
                    short8b v0 = *(const short8b*)hr;
                    short8b v1 = *(const short8b*)(hr + 8);
#pragma unroll
                    for (int i = 0; i < 8; ++i) {
                        sum[i]     += bf2f((unsigned short)v0[i]);
                        sum[8 + i] += bf2f((unsigned short)v1[i]);
                    }
                }
                float inv = 1.0f / (float)(cc > 0 ? cc : 1);
#pragma unroll
                for (int i = 0; i < 16; ++i) sum[i] *= inv;
            }
#pragma unroll
            for (int i = 0; i < 16; i += 4)
                *(float4*)&Hp[srow][scol + i] =
                    make_float4(sum[i], sum[i + 1], sum[i + 2], sum[i + 3]);
            short8b p0, p1;
#pragma unroll
            for (int i = 0; i < 8; ++i) { p0[i] = f2bf(sum[i]); p1[i] = f2bf(sum[8 + i]); }
            *(short8b*)&Ab[srow][scol] = p0;
            *(short8b*)&Ab[srow][scol + 8] = p1;
        }
        __syncthreads();

        // ---- gi loads (issue early, land under MFMA) ----
        int nodes_e[4];
        unsigned short gr[4][4] = {}, gz[4][4] = {}, gn[4][4] = {};
#pragma unroll
        for (int i = 0; i < 4; ++i) {
            int nd = Nd[kg * 4 + i];
            nodes_e[i] = nd;
            if (nd < N_NODES) {
                const unsigned short* gp = gi_all + (size_t)nd * G_DIM;
#pragma unroll
                for (int ns = 0; ns < 4; ++ns) {
                    int k = cb + ns * 16 + lr;
                    gr[ns][i] = gp[k];
                    gz[ns][i] = gp[256 + k];
                    gn[ns][i] = gp[512 + k];
                }
            }
        }

        // ---- A fragments from LDS ----
        short8b A[8];
#pragma unroll
        for (int ks = 0; ks < 8; ++ks)
            A[ks] = *(const short8b*)&Ab[lr][ks * 32 + kg * 8];

        // ---- GEMM: acc[c][ns] = h_prev @ w_hh^T ----
        const f32x4 zf = {0.f, 0.f, 0.f, 0.f};
        f32x4 acc[3][4];
#pragma unroll
        for (int c = 0; c < 3; ++c)
#pragma unroll
            for (int ns = 0; ns < 4; ++ns) acc[c][ns] = zf;

#pragma unroll
        for (int ks = 0; ks < 8; ++ks)
#pragma unroll
            for (int c = 0; c < 3; ++c)
#pragma unroll
                for (int ns = 0; ns < 4; ++ns) {
                    short8b B = *(const short8b*)(whb
                        + (size_t)(c * 256 + cb + ns * 16 + lr) * H_DIM
                        + ks * 32 + kg * 8);
                    acc[c][ns] = __builtin_amdgcn_mfma_f32_16x16x32_bf16(
                        A[ks], B, acc[c][ns], 0, 0, 0);
                }

        // ---- fused GRU epilogue ----
#pragma unroll
        for (int ns = 0; ns < 4; ++ns) {
            int k = cb + ns * 16 + lr;
#pragma unroll
            for (int i = 0; i < 4; ++i) {
                int nd = nodes_e[i];
                if (nd >= N_NODES) continue;
                int rl = kg * 4 + i;
                float xr = bf2f(gr[ns][i]) + acc[0][ns][i] + bh[0][ns];
                float xz = bf2f(gz[ns][i]) + acc[1][ns][i] + bh[1][ns];
                float r = 1.0f / (1.0f + expf(-xr));
                float z = 1.0f / (1.0f + expf(-xz));
                float n = tanhf(bf2f(gn[ns][i]) + r * (acc[2][ns][i] + bh[2][ns]));
                float h = (1.0f - z) * n + z * Hp[rl][k];
                if (d == 0) {
                    out[(size_t)(nd / S_NODES) * H_DIM + k] = h;
                } else {
                    h_all[(size_t)nd * H_DIM + k] = f2bf(h);
                }
            }
        }
    }
}

// ---------------------------------------------------------------------------
extern "C" void kernel_launch(void* const* d_in, const int* in_sizes, int n_in,
                              void* d_out, int out_size, void* d_ws, size_t ws_size,
                              hipStream_t stream) {
    const float* inputs = (const float*)d_in[0];
    const float* w_ih   = (const float*)d_in[1];
    const float* w_hh   = (const float*)d_in[2];
    const float* b_ih   = (const float*)d_in[3];
    const float* b_hh   = (const float*)d_in[4];
    const int* layer_nodes = (const int*)d_in[5];
    const int* child_idx   = (const int*)d_in[6];
    const int* child_cnt   = (const int*)d_in[7];

    const int LM = in_sizes[5];
    const int C  = in_sizes[6] / in_sizes[5];

    char* w = (char*)d_ws;
    size_t o = 0;
    auto alloc = [&](size_t bytes) {
        void* p = w + o;
        o += (bytes + 255) & ~(size_t)255;
        return p;
    };
    unsigned short* wib    = (unsigned short*)alloc((size_t)G_DIM * F_DIM * 2);
    unsigned short* whb    = (unsigned short*)alloc((size_t)G_DIM * H_DIM * 2);
    unsigned short* h_all  = (unsigned short*)alloc((size_t)N_NODES * H_DIM * 2);
    unsigned short* gi_all = (unsigned short*)alloc((size_t)N_NODES * G_DIM * 2);
    int*            Mdev      = (int*)alloc(4);
    int*            layer_cnt = (int*)alloc(D_MAX * 4);
    (void)ws_size;

    hipMemsetAsync(Mdev, 0x7F, 4, stream);                 // = 0x7F7F7F7F > LM
    hipMemsetAsync(layer_cnt, 0, D_MAX * 4, stream);

    k_zero<<<2048, 256, 0, stream>>>((float4*)h_all, N_NODES * H_DIM * 2 / 16);
    k_findM<<<256, 256, 0, stream>>>(layer_nodes, LM, Mdev);
    k_hist<<<256, 256, 0, stream>>>(layer_nodes, Mdev, layer_cnt, LM);
    k_convw<<<(G_DIM * F_DIM + 255) / 256, 256, 0, stream>>>(w_ih, w_hh, wib, whb);

    // One-shot feed-forward GEMM (b_ih folded in)
    k_gemm_x<<<(N_NODES + 255) / 256, 256, 0, stream>>>(inputs, wib, b_ih, gi_all);

    // Depth layers, deepest first (empty layers exit immediately)
    for (int d = D_MAX - 1; d >= 0; --d)
        k_layer<<<512, 256, 0, stream>>>(layer_nodes, child_idx, child_cnt,
                                         Mdev, layer_cnt, whb, gi_all, b_hh,
                                         h_all, (float*)d_out, d, C);
}